// Round 1
// baseline (155.580 us; speedup 1.0000x reference)
//
#include <hip/hip_runtime.h>
#include <hip/hip_cooperative_groups.h>

#define DENSE 2048
#define BATCH 64
#define MAXS  1024

namespace cg = cooperative_groups;

typedef __attribute__((ext_vector_type(8))) __bf16 bf16x8;
typedef __attribute__((ext_vector_type(4))) float f32x4;

// Fused single cooperative kernel.
//   Phase 0 (all 512 blocks): issue W f32x4 loads (HBM long pole) + cvt to bf16.
//   Phase 1 (blocks 0..63):  LDS histogram of spike_ids -> Cbf (bf16, MFMA
//                            A-fragment order, verified R2 absmax 1.0) + zero out.
//   grid.sync()              (release fence waits vmcnt(0) -> W latency hidden
//                            under phase 1 instead of serialized after it).
//   Phase 2 (all blocks):    bf16 MFMA 16x16x32 spmm, conflict-free LDS
//                            cross-wave reduce (R5 layout), atomicAdd to out.
//
// Cbf layout: lane = (b&15) | (((k>>3)&3)<<4) holds
//   C[b = mt*16+(lane&15)][k = ks*32+(lane>>4)*8+i]  (A-frag for 16x16x32 bf16).
//
// Grid linearization bid = ks4*128 + jt keeps a j-tile's 4 k-split atomic
// contenders congruent mod 8 -> same XCD/L2 under round-robin placement.

__global__ __launch_bounds__(256, 2) void fused_kernel(
        const int* __restrict__ ids, const int* __restrict__ ns,
        const float* __restrict__ W, __bf16* __restrict__ Cbf,
        float* __restrict__ out) {
    __shared__ int   cnt[DENSE];        // 8 KB  (phase 1, hist blocks only)
    __shared__ float P[4][4][4][64];    // 16 KB (phase 2 reduction)

    const int tid  = threadIdx.x;
    const int bid  = blockIdx.x;        // 0..511
    const int jt   = bid & 127;         // j tile
    const int ks4  = bid >> 7;          // 0..3 k split
    const int lane = tid & 63;
    const int wv   = tid >> 6;          // 0..3
    const int ln   = lane & 15;         // j index within tile (B-frag n)
    const int lq   = lane >> 4;         // k quad 0..3
    const int j0   = jt * 16;
    const int step0 = ks4 * 16 + wv * 4;
    const float* wrow = W + (size_t)(j0 + ln) * DENSE;

    // --- Phase 0: issue all W loads immediately (latency hides under hist)
    f32x4 w0[4], w1[4];
    #pragma unroll
    for (int s = 0; s < 4; ++s) {
        const int kbase = (step0 + s) * 32 + lq * 8;
        w0[s] = *(const f32x4*)(wrow + kbase);
        w1[s] = *(const f32x4*)(wrow + kbase + 4);
    }

    // --- Phase 1: histogram (blocks 0..63), one batch each + zero out row
    if (bid < BATCH) {
        const int b = bid;
        #pragma unroll
        for (int k = tid; k < DENSE; k += 256) cnt[k] = 0;
        __syncthreads();
        const int n = ns[b];
        const int4 v = ((const int4*)(ids + b * MAXS))[tid];  // 1024 = 256*int4
        const int base = tid * 4;
        if (base + 0 < n) atomicAdd(&cnt[v.x], 1);
        if (base + 1 < n) atomicAdd(&cnt[v.y], 1);
        if (base + 2 < n) atomicAdd(&cnt[v.z], 1);
        if (base + 3 < n) atomicAdd(&cnt[v.w], 1);
        __syncthreads();
        const int mt = b >> 4;
        const int bl = b & 15;
        #pragma unroll
        for (int k = tid; k < DENSE; k += 256) {
            const int l2 = bl | (((k >> 3) & 3) << 4);
            const size_t off = (size_t)(((k >> 5) * 4 + mt) * 64 + l2) * 8 + (k & 7);
            Cbf[off] = (__bf16)(float)cnt[k];
            out[(size_t)b * DENSE + k] = 0.0f;   // zero for phase-2 atomics
        }
    }

    // f32 -> bf16 conversion pre-sync: the grid.sync release fence waits
    // vmcnt(0) anyway; this takes 32 cvts off the post-sync critical path
    // and halves live regs across the barrier (wb=16 vs w0+w1=32).
    bf16x8 wb[4];
    #pragma unroll
    for (int s = 0; s < 4; ++s) {
        #pragma unroll
        for (int i = 0; i < 4; ++i) {
            wb[s][i]     = (__bf16)w0[s][i];
            wb[s][i + 4] = (__bf16)w1[s][i];
        }
    }

    cg::this_grid().sync();   // Cbf + out-zeros visible device-wide after this

    // --- Phase 2: A-frag loads (Cbf is L3-resident after the sync flush)
    bf16x8 afr[4][4];
    #pragma unroll
    for (int s = 0; s < 4; ++s) {
        #pragma unroll
        for (int mt = 0; mt < 4; ++mt) {
            afr[s][mt] = *(const bf16x8*)(Cbf + ((size_t)((step0 + s) * 4 + mt) * 64 + lane) * 8);
        }
    }

    f32x4 acc[4];
    #pragma unroll
    for (int mt = 0; mt < 4; ++mt) acc[mt] = (f32x4)0.0f;
    #pragma unroll
    for (int s = 0; s < 4; ++s) {
        #pragma unroll
        for (int mt = 0; mt < 4; ++mt) {
            acc[mt] = __builtin_amdgcn_mfma_f32_16x16x32_bf16(afr[s][mt], wb[s], acc[mt], 0, 0, 0);
        }
    }

    // --- cross-wave reduction, conflict-free layout P[wv][mt][r][lane] (R5)
    #pragma unroll
    for (int mt = 0; mt < 4; ++mt) {
        #pragma unroll
        for (int r = 0; r < 4; ++r) {
            P[wv][mt][r][lane] = acc[mt][r];
        }
    }
    __syncthreads();

    // thread t -> (jloc = t&15 fastest for coalesced atomics, bpart = t>>4)
    const int jloc  = tid & 15;
    const int bpart = tid >> 4;                       // 0..15
    const int lsrc  = ((bpart >> 2) << 4) | jloc;     // source lane
    const int r     = bpart & 3;                      // source acc reg
    #pragma unroll
    for (int mt = 0; mt < 4; ++mt) {
        const float v = P[0][mt][r][lsrc] + P[1][mt][r][lsrc]
                      + P[2][mt][r][lsrc] + P[3][mt][r][lsrc];
        atomicAdd(&out[(size_t)(mt * 16 + bpart) * DENSE + j0 + jloc], v);
    }
}

extern "C" void kernel_launch(void* const* d_in, const int* in_sizes, int n_in,
                              void* d_out, int out_size, void* d_ws, size_t ws_size,
                              hipStream_t stream) {
    const int*   ids = (const int*)d_in[0];   // [64, 1024] int32
    const int*   ns  = (const int*)d_in[1];   // [64] int32
    const float* W   = (const float*)d_in[2]; // [2048, 2048] float32
    float*  out = (float*)d_out;              // [64, 2048] float32
    __bf16* Cbf = (__bf16*)d_ws;              // 64*2048 bf16 = 256 KB

    void* args[] = {(void*)&ids, (void*)&ns, (void*)&W, (void*)&Cbf, (void*)&out};
    hipLaunchCooperativeKernel(fused_kernel, dim3(512), dim3(256), args, 0, stream);
}

// Round 2
// 73.834 us; speedup vs baseline: 2.1071x; 2.1071x over previous
//
#include <hip/hip_runtime.h>

#define DENSE 2048
#define BATCH 64
#define MAXS  1024

typedef __attribute__((ext_vector_type(8))) __bf16 bf16x8;
typedef __attribute__((ext_vector_type(4))) float f32x4;

// Two-kernel pipeline (R0 structure, 71.4 us proven; R1's cooperative fusion
// spent ~67 us idle in grid.sync -> reverted). Changes vs R0:
//   - spmm: one block owns a FULL j-tile (all k): grid 128 x 1024 thr
//     (16 waves x the proven 4-step MFMA structure), 16-way LDS reduce,
//     PLAIN stores -> no atomics, no out zero-init.
//   - hist: drops the out-zeroing (512 KB writes removed from critical path);
//     Cbf written as one coalesced bf16x8 (16 B) store per thread instead of
//     8 scattered 2 B stores.
//
// Cbf layout (verified R2, absmax 1.0): lane = (b&15) | (((k>>3)&3)<<4) holds
//   C[b = mt*16+(lane&15)][k = ks*32+(lane>>4)*8+i]  (A-frag, mfma 16x16x32 bf16)

__global__ __launch_bounds__(256) void hist_kernel(const int* __restrict__ ids,
                                                   const int* __restrict__ ns,
                                                   __bf16* __restrict__ Cbf) {
    __shared__ int cnt[DENSE];
    const int b = blockIdx.x;
    const int tid = threadIdx.x;
    // zero 2048 ints = 2 int4 per thread
    ((int4*)cnt)[tid]       = int4{0, 0, 0, 0};
    ((int4*)cnt)[tid + 256] = int4{0, 0, 0, 0};
    __syncthreads();
    const int n = ns[b];
    const int4 v = ((const int4*)(ids + b * MAXS))[tid];  // 1024 = 256*int4
    const int base = tid * 4;
    if (base + 0 < n) atomicAdd(&cnt[v.x], 1);
    if (base + 1 < n) atomicAdd(&cnt[v.y], 1);
    if (base + 2 < n) atomicAdd(&cnt[v.z], 1);
    if (base + 3 < n) atomicAdd(&cnt[v.w], 1);
    __syncthreads();
    // thread tid -> k = tid*8 .. tid*8+7: (k>>3)&3 = tid&3, k>>5 = tid>>2,
    // k&7 = 0..7 consecutive -> one aligned 16 B bf16x8 store.
    const int mt = b >> 4;
    const int bl = b & 15;
    const int l2 = bl | ((tid & 3) << 4);
    const size_t off = ((size_t)((tid >> 2) * 4 + mt) * 64 + l2) * 8;
    const int4 c0 = ((const int4*)cnt)[tid * 2];
    const int4 c1 = ((const int4*)cnt)[tid * 2 + 1];
    bf16x8 o;
    o[0] = (__bf16)(float)c0.x;  o[1] = (__bf16)(float)c0.y;
    o[2] = (__bf16)(float)c0.z;  o[3] = (__bf16)(float)c0.w;
    o[4] = (__bf16)(float)c1.x;  o[5] = (__bf16)(float)c1.y;
    o[6] = (__bf16)(float)c1.z;  o[7] = (__bf16)(float)c1.w;
    *(bf16x8*)(Cbf + off) = o;
}

// spmm: out[b][j] = sum_k C[b][k] * W[j][k] via bf16 MFMA 16x16x32.
// Block = j-tile (16 cols) x ALL k: 16 waves, wave wv does steps wv*4..wv*4+3
// (k = wv*128..wv*128+127). W loads issued first (HBM long pole), A-frags
// second (Cbf is L2/L3-resident). 16-way cross-wave reduce in LDS, plain
// coalesced stores. No atomics anywhere.
__global__ __launch_bounds__(1024, 1) void spmm_kernel(const float* __restrict__ W,
                                                       const __bf16* __restrict__ Cbf,
                                                       float* __restrict__ out) {
    __shared__ float P[16][16][64];     // 64 KB: [wave][mt*4+r][lane]

    const int tid  = threadIdx.x;
    const int lane = tid & 63;
    const int wv   = tid >> 6;          // 0..15
    const int j0   = blockIdx.x * 16;   // j tile
    const int ln   = lane & 15;         // j index within tile (B-frag n)
    const int lq   = lane >> 4;         // k quad 0..3
    const int step0 = wv * 4;
    const float* wrow = W + (size_t)(j0 + ln) * DENSE;

    // --- W loads first (HBM long pole; plain cached loads — NT regressed R3)
    f32x4 w0[4], w1[4];
    #pragma unroll
    for (int s = 0; s < 4; ++s) {
        const int kbase = (step0 + s) * 32 + lq * 8;
        w0[s] = *(const f32x4*)(wrow + kbase);
        w1[s] = *(const f32x4*)(wrow + kbase + 4);
    }
    // --- A-frag loads (L2/L3-resident)
    bf16x8 afr[4][4];
    #pragma unroll
    for (int s = 0; s < 4; ++s) {
        #pragma unroll
        for (int mt = 0; mt < 4; ++mt) {
            afr[s][mt] = *(const bf16x8*)(Cbf + ((size_t)((step0 + s) * 4 + mt) * 64 + lane) * 8);
        }
    }

    f32x4 acc[4];
    #pragma unroll
    for (int mt = 0; mt < 4; ++mt) acc[mt] = (f32x4)0.0f;
    #pragma unroll
    for (int s = 0; s < 4; ++s) {
        bf16x8 wb;                      // convert per-step: keeps peak regs <128
        #pragma unroll
        for (int i = 0; i < 4; ++i) {
            wb[i]     = (__bf16)w0[s][i];
            wb[i + 4] = (__bf16)w1[s][i];
        }
        #pragma unroll
        for (int mt = 0; mt < 4; ++mt) {
            acc[mt] = __builtin_amdgcn_mfma_f32_16x16x32_bf16(afr[s][mt], wb, acc[mt], 0, 0, 0);
        }
    }

    // --- 16-way cross-wave reduction in LDS, then plain stores
    #pragma unroll
    for (int mt = 0; mt < 4; ++mt) {
        #pragma unroll
        for (int r = 0; r < 4; ++r) {
            P[wv][mt * 4 + r][lane] = acc[mt][r];
        }
    }
    __syncthreads();

    // thread t -> output element (brow = t>>4 in 0..63, jloc = t&15 fastest
    // for coalesced stores). C/D layout: row = (lane>>4)*4 + reg, col = lane&15.
    const int jloc  = tid & 15;
    const int brow  = tid >> 4;                       // 0..63
    const int mt    = brow >> 4;
    const int bpart = brow & 15;
    const int lsrc  = ((bpart >> 2) << 4) | jloc;     // source lane
    const int r     = bpart & 3;                      // source acc reg
    float v = 0.0f;
    #pragma unroll
    for (int w = 0; w < 16; ++w) v += P[w][mt * 4 + r][lsrc];
    out[(size_t)brow * DENSE + j0 + jloc] = v;
}

extern "C" void kernel_launch(void* const* d_in, const int* in_sizes, int n_in,
                              void* d_out, int out_size, void* d_ws, size_t ws_size,
                              hipStream_t stream) {
    const int*   ids = (const int*)d_in[0];   // [64, 1024] int32
    const int*   ns  = (const int*)d_in[1];   // [64] int32
    const float* W   = (const float*)d_in[2]; // [2048, 2048] float32
    float*  out = (float*)d_out;              // [64, 2048] float32
    __bf16* Cbf = (__bf16*)d_ws;              // 64*2048 bf16 = 256 KB

    hipLaunchKernelGGL(hist_kernel, dim3(BATCH), dim3(256), 0, stream, ids, ns, Cbf);
    hipLaunchKernelGGL(spmm_kernel, dim3(DENSE / 16), dim3(1024), 0, stream, W, Cbf, out);
}